// Round 10
// baseline (44.234 us; speedup 1.0000x reference)
//
#include <hip/hip_runtime.h>

// out[d][c][h][w] = (h < d) ? left[c][h][w] - right[c][h + 128 - d][w] : 0
// N=1, C=16, H=128, W=256, D=128. Output (1,128,16,128,256) fp32 = 256 MiB.
//
// R10: 32x32-row super-tiles. A block stages 32 left rows + 32 right rows
// (64 KiB LDS) once; its 4 waves compute 16 8x8-row tiles (4 each,
// sequentially) from LDS. Reads: 10 staged blocks/channel x 64 KiB =
// 10 MiB total (vs 20 MiB in R9, 4 MiB compulsory floor).
// Stores: diagonal order within each tile (fixed a-b -> same d-slice,
// consecutive h). Zero region: slice pairs (d,127-d), 129 rows split 65/64
// across two waves (R5/R9 structure).
// NOTE: nt-stores regressed (R2,R4); L2-pinning futile (R8); BW-bound =>
// block-size imbalance is tolerable (stragglers get the whole bus).
//
// Per channel (42 blocks): r<6 cross-group (I<J of 4 32-row groups,
// 16 tiles); r<10 in-group (I==J: 6 off-diag + 4 diag tiles);
// r<42 zero blocks (128 zero waves/channel). Grid: 16*42 = 672.

typedef float f32x4 __attribute__((ext_vector_type(4)));

__device__ __forceinline__ void store_tile(f32x4* __restrict__ outl,
                                           const f32x4 (&L)[8],
                                           const f32x4 (&R)[8],
                                           int base) {
    // diagonal order: ab = a-b fixed -> same d-slice, consecutive h
#pragma unroll
    for (int ab = -7; ab <= 7; ++ab) {
        const int lo = ab > 0 ? ab : 0;
        const int hi = ab < 0 ? 7 + ab : 7;
#pragma unroll
        for (int a = lo; a <= hi; ++a) {
            const int b = a - ab;
            f32x4 o;
            o.x = L[a].x - R[b].x;
            o.y = L[a].y - R[b].y;
            o.z = L[a].z - R[b].z;
            o.w = L[a].w - R[b].w;
            outl[(base + a + ab * 2048) * 64] = o;
        }
    }
}

__device__ __forceinline__ void store_diag(f32x4* __restrict__ outl,
                                           const f32x4 (&L)[8],
                                           const f32x4 (&R)[8],
                                           int base) {
    // pairs a < b only (ab = a-b in [-7,-1])
#pragma unroll
    for (int ab = -7; ab <= -1; ++ab) {
#pragma unroll
        for (int a = 0; a <= 7 + ab; ++a) {
            const int b = a - ab;
            f32x4 o;
            o.x = L[a].x - R[b].x;
            o.y = L[a].y - R[b].y;
            o.z = L[a].z - R[b].z;
            o.w = L[a].w - R[b].w;
            outl[(base + a + ab * 2048) * 64] = o;
        }
    }
}

__global__ __launch_bounds__(256) void CostDifference_kernel(
    const f32x4* __restrict__ left,
    const f32x4* __restrict__ right,
    f32x4* __restrict__ out)
{
    __shared__ f32x4 lds[64][64];                // 64 KiB: 32 L rows + 32 R rows
    const int lane = threadIdx.x & 63;
    const int w    = threadIdx.x >> 6;

    const int c = blockIdx.x / 42;               // block-uniform
    const int r = blockIdx.x - c * 42;

    if (r < 10) {
        // ---- staged super-tile block ----
        int I, J;
        if (r < 6) {                             // cross pair (I<J) of 4 groups
            int p = r; I = 0;
            while (p >= 3 - I) { p -= 3 - I; ++I; }
            J = I + 1 + p;
        } else {
            I = J = r - 6;                       // in-group
        }

        // cooperative stage: 64 rows; wave w loads rows w, w+4, ..., w+60
        const int base_l = (c * 128 + (I << 5)) * 64 + lane;
        const int base_r = (c * 128 + (J << 5)) * 64 + lane;
#pragma unroll
        for (int k = 0; k < 16; ++k) {
            const int row = (k << 2) + w;        // wave-uniform per k
            lds[row][lane] = (row < 32) ? left [base_l + (row << 6)]
                                        : right[base_r + ((row - 32) << 6)];
        }
        __syncthreads();

        f32x4 L[8], R[8];
        if (r < 6) {
            // cross: wave w owns left sub-block ai=w; 4 tiles over bj
            const int i8 = (I << 5) + (w << 3);
#pragma unroll
            for (int a = 0; a < 8; ++a) L[a] = lds[(w << 3) + a][lane];
            for (int bj = 0; bj < 4; ++bj) {
#pragma unroll
                for (int b = 0; b < 8; ++b) R[b] = lds[32 + (bj << 3) + b][lane];
                const int j8 = (J << 5) + (bj << 3);
                store_tile(out + lane, L, R,
                           (128 + i8 - j8) * 2048 + c * 128 + i8);
            }
        } else {
            // in-group: off-diag tiles (ai<bj) on w0/w1, diag tiles on w2/w3
            if (w < 2) {
                for (int t = 0; t < 3; ++t) {
                    const int ai = (w == 0) ? 0 : ((t < 2) ? 1 : 2);
                    const int bj = (w == 0) ? (t + 1) : ((t < 2) ? (t + 2) : 3);
#pragma unroll
                    for (int a = 0; a < 8; ++a) L[a] = lds[(ai << 3) + a][lane];
#pragma unroll
                    for (int b = 0; b < 8; ++b) R[b] = lds[32 + (bj << 3) + b][lane];
                    const int i8 = (I << 5) + (ai << 3);
                    const int j8 = (I << 5) + (bj << 3);
                    store_tile(out + lane, L, R,
                               (128 + i8 - j8) * 2048 + c * 128 + i8);
                }
            } else {
                for (int t = 0; t < 2; ++t) {
                    const int ai = ((w - 2) << 1) | t;
#pragma unroll
                    for (int a = 0; a < 8; ++a) L[a] = lds[(ai << 3) + a][lane];
#pragma unroll
                    for (int b = 0; b < 8; ++b) R[b] = lds[32 + (ai << 3) + b][lane];
                    const int i8 = (I << 5) + (ai << 3);
                    store_diag(out + lane, L, R,
                               128 * 2048 + c * 128 + i8);
                }
            }
        }
    } else {
        // ---- zero waves: slice pair (d, 127-d), 129 rows split 65/64 ----
        const int t    = ((r - 10) << 2) | w;    // 0..127, wave-uniform
        const int d    = t >> 1;                 // 0..63
        const int half = t & 1;
        const int d2   = 127 - d;
        const int n1   = 128 - d;                // zero rows in slice d
        const int start = half ? 65 : 0;
        const int end   = half ? 129 : 65;
        const f32x4 zero = {0.f, 0.f, 0.f, 0.f};

        // slice d: rows d+kk for kk in [start, min(end, n1))
        const int e1 = min(end, n1);
        int rb = (d * 2048 + c * 128 + d + start) * 64 + lane;
        for (int kk = start; kk < e1; ++kk, rb += 64) out[rb] = zero;

        // slice d2: rows d2+(kk-n1) for kk in [max(start, n1), end)
        const int s2 = max(start, n1);
        rb = (d2 * 2048 + c * 128 + d2 + (s2 - n1)) * 64 + lane;
        for (int kk = s2; kk < end; ++kk, rb += 64) out[rb] = zero;
    }
}

extern "C" void kernel_launch(void* const* d_in, const int* in_sizes, int n_in,
                              void* d_out, int out_size, void* d_ws, size_t ws_size,
                              hipStream_t stream) {
    const f32x4* left  = (const f32x4*)d_in[0];
    const f32x4* right = (const f32x4*)d_in[1];
    f32x4* out = (f32x4*)d_out;

    CostDifference_kernel<<<672, 256, 0, stream>>>(left, right, out);
}